// Round 1
// baseline (1195.814 us; speedup 1.0000x reference)
//
#include <hip/hip_runtime.h>

// ---------------- problem constants ----------------
#define E_EDGES 64800
#define NC      842
#define NB      8          // b*t = 2*4
#define FIN     78
#define HD      256
#define E_LAT   5894
#define NROWS_NODE (NB*NC)   // 6736

// output layout (flat float32)
#define OUT_NODES_N   1724416          // 8*842*256
#define OUT_IDX_OFF   1724416
#define OUT_IDX_N     11788            // 2*5894
#define OUT_ATTR_OFF  1736204

// workspace layout (bytes)
#define AGG_OFF    0
#define AGG_BYTES  6897664             // 8*842*256*4
#define CNT_OFF    6897664
#define CUR_OFF    6901032
#define PERM_OFF   6904400
#define WPACK_OFF  7163904             // 1KB aligned

// packed-weight element offsets (bf16 elements)
#define WOFF_E0 0
#define WOFF_E1 40960
#define WOFF_E2 106496
#define WOFF_N0 172032
#define WOFF_N1 262144
#define WOFF_N2 327680
#define WOFF_R0 393216
#define WOFF_R1 401408
#define WOFF_R2 466944

typedef __bf16 bf16x8 __attribute__((ext_vector_type(8)));
typedef float  f32x4  __attribute__((ext_vector_type(4)));

__device__ __forceinline__ unsigned short f2bf(float f) {
    unsigned u = __builtin_bit_cast(unsigned, f);
    return (unsigned short)((u + 0x7fffu + ((u >> 16) & 1u)) >> 16);  // RNE
}
__device__ __forceinline__ float leakyf(float v) { return v > 0.f ? v : 0.01f * v; }

__device__ __forceinline__ void zero_acc(f32x4 (&acc)[4][4]) {
#pragma unroll
    for (int mf = 0; mf < 4; ++mf)
#pragma unroll
        for (int nf = 0; nf < 4; ++nf)
            acc[mf][nf] = (f32x4){0.f, 0.f, 0.f, 0.f};
}

// One GEMM layer: C[64x(wave 64-col slice)] += A_lds[64 x 32*nks] * Wpacked
// A-frag:  A[m=lane&15][k=q*8+j]  (ds_read_b128, stride chosen bank-friendly)
// B-frag:  packed linear: chunk(kk,nfg) = 1KB, lane*16B (global dwordx4, L2-hot)
__device__ __forceinline__ void run_layer(const unsigned short* lA, int strideA,
                                          const unsigned short* Wp, int nks, int nfg0,
                                          int m15, int q, int lane, f32x4 (&acc)[4][4]) {
    for (int kk = 0; kk < nks; ++kk) {
        bf16x8 a[4];
#pragma unroll
        for (int mf = 0; mf < 4; ++mf)
            a[mf] = *(const bf16x8*)(lA + (mf * 16 + m15) * strideA + kk * 32 + q * 8);
#pragma unroll
        for (int nf = 0; nf < 4; ++nf) {
            bf16x8 b = *(const bf16x8*)(Wp + (size_t)(kk * 16 + nfg0 + nf) * 512 + lane * 8);
#pragma unroll
            for (int mf = 0; mf < 4; ++mf)
                acc[mf][nf] = __builtin_amdgcn_mfma_f32_16x16x32_bf16(a[mf], b, acc[mf][nf], 0, 0, 0);
        }
    }
}

// epilogue: H[row*264+col] = bf16(leaky(acc + bias[col]));  C/D: row=q*4+reg, col=lane&15
__device__ __forceinline__ void epi_to_H(unsigned short* Hb, const f32x4 (&acc)[4][4],
                                         const float* bias, int w, int m15, int q) {
#pragma unroll
    for (int nf = 0; nf < 4; ++nf) {
        int col = w * 64 + nf * 16 + m15;
        float bv = bias[col];
#pragma unroll
        for (int mf = 0; mf < 4; ++mf)
#pragma unroll
            for (int r4 = 0; r4 < 4; ++r4) {
                int row = mf * 16 + q * 4 + r4;
                Hb[row * 264 + col] = f2bf(leakyf(acc[mf][nf][r4] + bv));
            }
    }
}

// ---------------- weight packing ----------------
__global__ void pack_weights(const float* s0, const float* s1, const float* s2,
                             const float* s3, const float* s4, const float* s5,
                             const float* s6, const float* s7, const float* s8,
                             unsigned short* wp) {
    const int ksA[9]  = {5, 8, 8, 11, 8, 8, 1, 8, 8};
    const int kaA[9]  = {158, 256, 256, 334, 256, 256, 2, 256, 256};
    const int offA[9] = {WOFF_E0, WOFF_E1, WOFF_E2, WOFF_N0, WOFF_N1, WOFF_N2,
                         WOFF_R0, WOFF_R1, WOFF_R2};
    const float* srcs[9] = {s0, s1, s2, s3, s4, s5, s6, s7, s8};
    int rem = blockIdx.x;
    int l = 0;
    while (rem >= ksA[l] * 16) { rem -= ksA[l] * 16; ++l; }
    int kk = rem >> 4, nf = rem & 15;
    int lane = threadIdx.x >> 3, j = threadIdx.x & 7;
    int k = kk * 32 + (lane >> 4) * 8 + j;
    int n = nf * 16 + (lane & 15);
    float v = (k < kaA[l]) ? srcs[l][k * 256 + n] : 0.f;
    wp[(size_t)offA[l] + (size_t)(blockIdx.x * 0 + (kk * 16 + nf)) * 512 + lane * 8 + j] = f2bf(v);
}

// ---------------- counting sort of edges by dst ----------------
__global__ void hist_kernel(const int* __restrict__ dstA, int* __restrict__ cnt) {
    int e = blockIdx.x * 256 + threadIdx.x;
    if (e < E_EDGES) atomicAdd(&cnt[dstA[e]], 1);
}
__global__ void scan_kernel(const int* __restrict__ cnt, int* __restrict__ cursor) {
    __shared__ int s[1024];
    int t = threadIdx.x;
    s[t] = (t < NC) ? cnt[t] : 0;
    __syncthreads();
    for (int d = 1; d < 1024; d <<= 1) {
        int v = (t >= d) ? s[t - d] : 0;
        __syncthreads();
        s[t] += v;
        __syncthreads();
    }
    if (t < NC) cursor[t] = (t == 0) ? 0 : s[t - 1];
}
__global__ void scatter_kernel(const int* __restrict__ dstA, int* __restrict__ cursor,
                               int* __restrict__ perm) {
    int e = blockIdx.x * 256 + threadIdx.x;
    if (e < E_EDGES) {
        int p = atomicAdd(&cursor[dstA[e]], 1);
        perm[p] = e;
    }
}

// ---------------- fused 3-layer edge MLP + segment reduce ----------------
union EdgeSh {
    struct { unsigned short A[64 * 168]; unsigned short H[64 * 264]; } s;
    float M[64 * 257];
};

__global__ __launch_bounds__(256, 2) void edge_mlp_kernel(
    const float* __restrict__ x, const int* __restrict__ edge_index,
    const float* __restrict__ eattr, const float* __restrict__ h3,
    const float* __restrict__ eb0, const float* __restrict__ eb1, const float* __restrict__ eb2,
    const unsigned short* __restrict__ wpack, const int* __restrict__ perm,
    float* __restrict__ agg) {
    const int* srcA = edge_index;
    const int* dstA = edge_index + E_EDGES;
    __shared__ __align__(16) EdgeSh u;
    __shared__ int dstl[64], srcl[64], eidl[64];

    const int tile = blockIdx.x, b = blockIdx.y;
    const int base = tile * 64;
    const int tid = threadIdx.x, lane = tid & 63, w = tid >> 6;
    const int m15 = lane & 15, q = lane >> 4;

    if (tid < 64) {
        int eg = base + tid;
        int e = (eg < E_EDGES) ? perm[eg] : -1;
        eidl[tid] = e;
        srcl[tid] = (e >= 0) ? srcA[e] : -1;
        dstl[tid] = (e >= 0) ? dstA[e] : -1;
    }
    __syncthreads();

    // stage e_in = [x[b,src], h3[dst], attr] as bf16, stride 168, zero-padded
    const size_t xbase = (size_t)b * (E_EDGES * FIN);
    for (int i = tid; i < 64 * 168; i += 256) {
        int r = i / 168, k = i - r * 168;
        float v = 0.f;
        int s = srcl[r];
        if (s >= 0) {
            if (k < 78) v = x[xbase + (size_t)s * 78 + k];
            else if (k < 156) v = h3[dstl[r] * 78 + (k - 78)];
            else if (k < 158) v = eattr[eidl[r] * 2 + (k - 156)];
        }
        u.s.A[i] = f2bf(v);
    }
    __syncthreads();

    f32x4 acc[4][4];
    zero_acc(acc);
    run_layer(u.s.A, 168, wpack + WOFF_E0, 5, w * 4, m15, q, lane, acc);   // K=160
    epi_to_H(u.s.H, acc, eb0, w, m15, q);
    __syncthreads();

    zero_acc(acc);
    run_layer(u.s.H, 264, wpack + WOFF_E1, 8, w * 4, m15, q, lane, acc);   // K=256
    __syncthreads();            // all reads of H done before overwrite
    epi_to_H(u.s.H, acc, eb1, w, m15, q);
    __syncthreads();

    zero_acc(acc);
    run_layer(u.s.H, 264, wpack + WOFF_E2, 8, w * 4, m15, q, lane, acc);   // K=256
    __syncthreads();            // H reads done before M (aliases A+H) is written

    // msgs (fp32, + bias, NO activation) into LDS
#pragma unroll
    for (int nf = 0; nf < 4; ++nf) {
        int col = w * 64 + nf * 16 + m15;
        float bv = eb2[col];
#pragma unroll
        for (int mf = 0; mf < 4; ++mf)
#pragma unroll
            for (int r4 = 0; r4 < 4; ++r4) {
                int row = mf * 16 + q * 4 + r4;
                u.M[row * 257 + col] = acc[mf][nf][r4] + bv;
            }
    }
    __syncthreads();

    // segment-sum down the sorted 64-row tile: thread t owns column t
    {
        int col = tid;
        float run = 0.f;
        int cur = dstl[0];
        for (int r = 0; r < 64; ++r) {
            int d = dstl[r];
            if (d < 0) break;               // padding rows are at the tail
            if (d != cur) {
                atomicAdd(&agg[((size_t)b * NC + cur) * 256 + col], run);
                run = 0.f;
                cur = d;
            }
            run += u.M[r * 257 + col];
        }
        if (cur >= 0) atomicAdd(&agg[((size_t)b * NC + cur) * 256 + col], run);
    }
}

// ---------------- node MLP ----------------
__global__ __launch_bounds__(256, 2) void node_mlp_kernel(
    const float* __restrict__ h3, const float* __restrict__ agg,
    const float* __restrict__ nb0, const float* __restrict__ nb1, const float* __restrict__ nb2,
    const unsigned short* __restrict__ wpack, float* __restrict__ out) {
    __shared__ __align__(16) unsigned short As[64 * 360];
    __shared__ __align__(16) unsigned short Hs[64 * 264];
    __shared__ int cl[64], vl[64];

    const int base = blockIdx.x * 64;
    const int tid = threadIdx.x, lane = tid & 63, w = tid >> 6;
    const int m15 = lane & 15, q = lane >> 4;

    if (tid < 64) {
        int jj = base + tid;
        vl[tid] = (jj < NROWS_NODE);
        cl[tid] = vl[tid] ? (jj % NC) : 0;
    }
    __syncthreads();

    for (int i = tid; i < 64 * 360; i += 256) {
        int r = i / 360, k = i - r * 360;
        float v = 0.f;
        if (vl[r]) {
            int jj = base + r;
            if (k < 78) v = h3[cl[r] * 78 + k];
            else if (k < 334) v = agg[(size_t)jj * 256 + (k - 78)];
        }
        As[i] = f2bf(v);
    }
    __syncthreads();

    f32x4 acc[4][4];
    zero_acc(acc);
    run_layer(As, 360, wpack + WOFF_N0, 11, w * 4, m15, q, lane, acc);   // K=352
    epi_to_H(Hs, acc, nb0, w, m15, q);
    __syncthreads();

    zero_acc(acc);
    run_layer(Hs, 264, wpack + WOFF_N1, 8, w * 4, m15, q, lane, acc);
    __syncthreads();
    epi_to_H(Hs, acc, nb1, w, m15, q);
    __syncthreads();

    zero_acc(acc);
    run_layer(Hs, 264, wpack + WOFF_N2, 8, w * 4, m15, q, lane, acc);

#pragma unroll
    for (int nf = 0; nf < 4; ++nf) {
        int col = w * 64 + nf * 16 + m15;
        float bv = nb2[col];
#pragma unroll
        for (int mf = 0; mf < 4; ++mf)
#pragma unroll
            for (int r4 = 0; r4 < 4; ++r4) {
                int row = mf * 16 + q * 4 + r4;
                int jj = base + row;
                if (jj < NROWS_NODE) out[(size_t)jj * 256 + col] = acc[mf][nf][r4] + bv;
            }
    }
}

// ---------------- residual MLP over latent edge attrs ----------------
__global__ __launch_bounds__(256, 2) void res_mlp_kernel(
    const float* __restrict__ la, const float* __restrict__ rb0, const float* __restrict__ rb1,
    const float* __restrict__ rb2, const float* __restrict__ rWs, const float* __restrict__ rbs,
    const unsigned short* __restrict__ wpack, float* __restrict__ out) {
    __shared__ __align__(16) unsigned short As[64 * 40];
    __shared__ __align__(16) unsigned short Hs[64 * 264];

    const int base = blockIdx.x * 64;
    const int tid = threadIdx.x, lane = tid & 63, w = tid >> 6;
    const int m15 = lane & 15, q = lane >> 4;

    for (int i = tid; i < 64 * 40; i += 256) {
        int r = i / 40, k = i - r * 40;
        int e = base + r;
        float v = (e < E_LAT && k < 2) ? la[e * 2 + k] : 0.f;
        As[i] = f2bf(v);
    }
    __syncthreads();

    f32x4 acc[4][4];
    zero_acc(acc);
    run_layer(As, 40, wpack + WOFF_R0, 1, w * 4, m15, q, lane, acc);   // K=32 (2 real)
    epi_to_H(Hs, acc, rb0, w, m15, q);
    __syncthreads();

    zero_acc(acc);
    run_layer(Hs, 264, wpack + WOFF_R1, 8, w * 4, m15, q, lane, acc);
    __syncthreads();
    epi_to_H(Hs, acc, rb1, w, m15, q);
    __syncthreads();

    zero_acc(acc);
    run_layer(Hs, 264, wpack + WOFF_R2, 8, w * 4, m15, q, lane, acc);

#pragma unroll
    for (int nf = 0; nf < 4; ++nf) {
        int col = w * 64 + nf * 16 + m15;
        float bv = rb2[col] + rbs[col];
        float ws0 = rWs[col], ws1 = rWs[256 + col];
#pragma unroll
        for (int mf = 0; mf < 4; ++mf)
#pragma unroll
            for (int r4 = 0; r4 < 4; ++r4) {
                int row = mf * 16 + q * 4 + r4;
                int e = base + row;
                if (e < E_LAT) {
                    float v = acc[mf][nf][r4] + bv + la[e * 2] * ws0 + la[e * 2 + 1] * ws1;
                    out[(size_t)e * 256 + col] = v;
                }
            }
    }
}

__global__ void idx_copy_kernel(const int* __restrict__ lei, float* __restrict__ out) {
    int i = blockIdx.x * 256 + threadIdx.x;
    if (i < OUT_IDX_N) out[i] = (float)lei[i];
}

// ---------------- launch ----------------
extern "C" void kernel_launch(void* const* d_in, const int* in_sizes, int n_in,
                              void* d_out, int out_size, void* d_ws, size_t ws_size,
                              hipStream_t stream) {
    const float* x      = (const float*)d_in[0];
    const int*   eidx   = (const int*)d_in[1];
    const float* eattr  = (const float*)d_in[2];
    const int*   lei    = (const int*)d_in[3];
    const float* la     = (const float*)d_in[4];
    const float* h3     = (const float*)d_in[5];
    const float* eW0 = (const float*)d_in[6],  *eb0 = (const float*)d_in[7];
    const float* eW1 = (const float*)d_in[8],  *eb1 = (const float*)d_in[9];
    const float* eW2 = (const float*)d_in[10], *eb2 = (const float*)d_in[11];
    const float* nW0 = (const float*)d_in[12], *nb0 = (const float*)d_in[13];
    const float* nW1 = (const float*)d_in[14], *nb1 = (const float*)d_in[15];
    const float* nW2 = (const float*)d_in[16], *nb2 = (const float*)d_in[17];
    const float* rW0 = (const float*)d_in[18], *rb0 = (const float*)d_in[19];
    const float* rW1 = (const float*)d_in[20], *rb1 = (const float*)d_in[21];
    const float* rW2 = (const float*)d_in[22], *rb2 = (const float*)d_in[23];
    const float* rWs = (const float*)d_in[24], *rbs = (const float*)d_in[25];

    char* ws = (char*)d_ws;
    float* agg  = (float*)(ws + AGG_OFF);
    int* cnt    = (int*)(ws + CNT_OFF);
    int* cur    = (int*)(ws + CUR_OFF);
    int* perm   = (int*)(ws + PERM_OFF);
    unsigned short* wpack = (unsigned short*)(ws + WPACK_OFF);

    float* out = (float*)d_out;

    // zero agg + histogram counters (cursor/perm/wpack fully overwritten below)
    hipMemsetAsync(d_ws, 0, CUR_OFF, stream);

    pack_weights<<<1040, 512, 0, stream>>>(eW0, eW1, eW2, nW0, nW1, nW2, rW0, rW1, rW2, wpack);
    hist_kernel<<<254, 256, 0, stream>>>(eidx + E_EDGES, cnt);
    scan_kernel<<<1, 1024, 0, stream>>>(cnt, cur);
    scatter_kernel<<<254, 256, 0, stream>>>(eidx + E_EDGES, cur, perm);

    edge_mlp_kernel<<<dim3(1013, NB), 256, 0, stream>>>(x, eidx, eattr, h3,
                                                        eb0, eb1, eb2, wpack, perm, agg);
    node_mlp_kernel<<<106, 256, 0, stream>>>(h3, agg, nb0, nb1, nb2, wpack, out);
    res_mlp_kernel<<<93, 256, 0, stream>>>(la, rb0, rb1, rb2, rWs, rbs, wpack,
                                           out + OUT_ATTR_OFF);
    idx_copy_kernel<<<47, 256, 0, stream>>>(lei, out + OUT_IDX_OFF);
}

// Round 2
// 948.446 us; speedup vs baseline: 1.2608x; 1.2608x over previous
//
#include <hip/hip_runtime.h>

// ---------------- problem constants ----------------
#define E_EDGES 64800
#define NC      842
#define NB      8          // b*t = 2*4
#define FIN     78
#define E_LAT   5894
#define NROWS_NODE (NB*NC)   // 6736
#define NTILES_E 1013        // ceil(64800/64)

// output layout (flat float32)
#define OUT_IDX_OFF   1724416
#define OUT_IDX_N     11788
#define OUT_ATTR_OFF  1736204

// workspace layout (bytes)
#define AGG_OFF    0
#define CNT_OFF    6897664
#define CUR_OFF    6901032
#define PERM_OFF   6904400
#define WPACK_OFF  7163904

// packed-weight element offsets (bf16 elements)
#define WOFF_E0 0
#define WOFF_E1 40960
#define WOFF_E2 106496
#define WOFF_N0 172032
#define WOFF_N1 262144
#define WOFF_N2 327680
#define WOFF_R0 393216
#define WOFF_R1 401408
#define WOFF_R2 466944

// LDS strides (bf16 elems): odd dword counts (81, 129, 181, 21) -> conflict-free b128 reads
#define SA_E 162
#define SH   258
#define SA_N 362
#define SA_R 42

typedef __bf16 bf16x8 __attribute__((ext_vector_type(8)));
typedef float  f32x4  __attribute__((ext_vector_type(4)));

__device__ __forceinline__ unsigned short f2bf(float f) {
    unsigned u = __builtin_bit_cast(unsigned, f);
    return (unsigned short)((u + 0x7fffu + ((u >> 16) & 1u)) >> 16);  // RNE
}
__device__ __forceinline__ unsigned packbf2(float lo, float hi) {
    return (unsigned)f2bf(lo) | ((unsigned)f2bf(hi) << 16);
}
__device__ __forceinline__ float leakyf(float v) { return v > 0.f ? v : 0.01f * v; }

template<int MF>
__device__ __forceinline__ void zero_acc(f32x4 (&acc)[MF][4]) {
#pragma unroll
    for (int mf = 0; mf < MF; ++mf)
#pragma unroll
        for (int nf = 0; nf < 4; ++nf)
            acc[mf][nf] = (f32x4){0.f, 0.f, 0.f, 0.f};
}

// C[MF*16 rows x 64-col wave slice] += A_lds * Wpacked
template<int MF>
__device__ __forceinline__ void run_layer(const unsigned short* lA, int strideA,
                                          const unsigned short* Wp, int nks, int nfg0,
                                          int m15, int q, int lane, f32x4 (&acc)[MF][4]) {
    for (int kk = 0; kk < nks; ++kk) {
        bf16x8 a[MF];
#pragma unroll
        for (int mf = 0; mf < MF; ++mf)
            a[mf] = *(const bf16x8*)(lA + (mf * 16 + m15) * strideA + kk * 32 + q * 8);
#pragma unroll
        for (int nf = 0; nf < 4; ++nf) {
            bf16x8 b = *(const bf16x8*)(Wp + (size_t)(kk * 16 + nfg0 + nf) * 512 + lane * 8);
#pragma unroll
            for (int mf = 0; mf < MF; ++mf)
                acc[mf][nf] = __builtin_amdgcn_mfma_f32_16x16x32_bf16(a[mf], b, acc[mf][nf], 0, 0, 0);
        }
    }
}

// H[row*SH+col] = bf16(leaky(acc + bias[col]))
template<int MF>
__device__ __forceinline__ void epi_to_H(unsigned short* Hb, const f32x4 (&acc)[MF][4],
                                         const float* bias, int w, int m15, int q) {
#pragma unroll
    for (int nf = 0; nf < 4; ++nf) {
        int col = w * 64 + nf * 16 + m15;
        float bv = bias[col];
#pragma unroll
        for (int mf = 0; mf < MF; ++mf)
#pragma unroll
            for (int r4 = 0; r4 < 4; ++r4) {
                int row = mf * 16 + q * 4 + r4;
                Hb[row * SH + col] = f2bf(leakyf(acc[mf][nf][r4] + bv));
            }
    }
}

// ---------------- weight packing ----------------
__global__ void pack_weights(const float* s0, const float* s1, const float* s2,
                             const float* s3, const float* s4, const float* s5,
                             const float* s6, const float* s7, const float* s8,
                             unsigned short* wp) {
    const int ksA[9]  = {5, 8, 8, 11, 8, 8, 1, 8, 8};
    const int kaA[9]  = {158, 256, 256, 334, 256, 256, 2, 256, 256};
    const int offA[9] = {WOFF_E0, WOFF_E1, WOFF_E2, WOFF_N0, WOFF_N1, WOFF_N2,
                         WOFF_R0, WOFF_R1, WOFF_R2};
    const float* srcs[9] = {s0, s1, s2, s3, s4, s5, s6, s7, s8};
    int rem = blockIdx.x;
    int l = 0;
    while (rem >= ksA[l] * 16) { rem -= ksA[l] * 16; ++l; }
    int kk = rem >> 4, nf = rem & 15;
    int lane = threadIdx.x >> 3, j = threadIdx.x & 7;
    int k = kk * 32 + (lane >> 4) * 8 + j;
    int n = nf * 16 + (lane & 15);
    float v = (k < kaA[l]) ? srcs[l][k * 256 + n] : 0.f;
    wp[(size_t)offA[l] + (size_t)(kk * 16 + nf) * 512 + lane * 8 + j] = f2bf(v);
}

// ---------------- counting sort of edges by dst ----------------
__global__ void hist_kernel(const int* __restrict__ dstA, int* __restrict__ cnt) {
    int e = blockIdx.x * 256 + threadIdx.x;
    if (e < E_EDGES) atomicAdd(&cnt[dstA[e]], 1);
}
__global__ void scan_kernel(const int* __restrict__ cnt, int* __restrict__ cursor) {
    __shared__ int s[1024];
    int t = threadIdx.x;
    s[t] = (t < NC) ? cnt[t] : 0;
    __syncthreads();
    for (int d = 1; d < 1024; d <<= 1) {
        int v = (t >= d) ? s[t - d] : 0;
        __syncthreads();
        s[t] += v;
        __syncthreads();
    }
    if (t < NC) cursor[t] = (t == 0) ? 0 : s[t - 1];
}
__global__ void scatter_kernel(const int* __restrict__ dstA, int* __restrict__ cursor,
                               int* __restrict__ perm) {
    int e = blockIdx.x * 256 + threadIdx.x;
    if (e < E_EDGES) {
        int p = atomicAdd(&cursor[dstA[e]], 1);
        perm[p] = e;
    }
}

// ---------------- fused 3-layer edge MLP, 8-batch loop, in-register segment reduce ----
__global__ __launch_bounds__(256, 3) void edge_mlp_kernel(
    const float* __restrict__ x, const int* __restrict__ edge_index,
    const float* __restrict__ eattr, const float* __restrict__ h3,
    const float* __restrict__ eb0, const float* __restrict__ eb1, const float* __restrict__ eb2,
    const unsigned short* __restrict__ wpack, const int* __restrict__ perm,
    float* __restrict__ agg) {
    const int* srcA = edge_index;
    const int* dstA = edge_index + E_EDGES;
    __shared__ __align__(16) unsigned short As[64 * SA_E];   // [x(78) | h3(78) | attr(2) | pad(4)]
    __shared__ __align__(16) unsigned short Hs[64 * SH];
    __shared__ short dstl[64];
    __shared__ unsigned short srcl[64];
    __shared__ unsigned char starts[68];
    __shared__ int nseg;

    const int base = blockIdx.x * 64;
    const int tid = threadIdx.x, lane = tid & 63, w = tid >> 6;
    const int m15 = lane & 15, q = lane >> 4;

    if (tid < 64) {
        int eg = base + tid;
        int e = (eg < E_EDGES) ? perm[eg] : -1;
        dstl[tid] = (e >= 0) ? (short)dstA[e] : (short)-1;
        srcl[tid] = (e >= 0) ? (unsigned short)srcA[e] : 0;
    }
    __syncthreads();

    // --- stage batch-invariant half of layer-0 input: cols 78..161 ---
    {
        int rr = tid >> 2, j = tid & 3;
        int d = dstl[rr];
        if (d >= 0) {
            const float* hr = h3 + d * FIN;
            for (int p = j; p < 39; p += 4) {
                float2 f = *(const float2*)(hr + 2 * p);
                *(unsigned*)(As + rr * SA_E + 78 + 2 * p) = packbf2(f.x, f.y);
            }
            if (j == 3) {
                int e = perm[base + rr];
                float2 f = *(const float2*)(eattr + e * 2);
                *(unsigned*)(As + rr * SA_E + 156) = packbf2(f.x, f.y);
                *(unsigned*)(As + rr * SA_E + 158) = 0;
                *(unsigned*)(As + rr * SA_E + 160) = 0;
            }
        } else {
            for (int p = j; p < 42; p += 4)
                *(unsigned*)(As + rr * SA_E + 78 + 2 * p) = 0;
        }
    }
    // --- segment starts (batch-invariant) ---
    if (tid == 0) {
        int ns = 0; short prev = -2; int r = 0;
        for (; r < 64; ++r) {
            short d = dstl[r];
            if (d < 0) break;
            if (d != prev) { starts[ns++] = (unsigned char)r; prev = d; }
        }
        starts[ns] = (unsigned char)r;
        nseg = ns;
    }

    float bnf[4];
#pragma unroll
    for (int nf = 0; nf < 4; ++nf) bnf[nf] = eb2[w * 64 + nf * 16 + m15];
    __syncthreads();

    const int rr = tid >> 2, j = tid & 3;
    const int rvalid = (dstl[rr] >= 0);
    const float* xrow0 = x + (size_t)srcl[rr] * FIN;

    for (int b = 0; b < NB; ++b) {
        // --- stage x part: cols 0..77 ---
        {
            const float* xr = xrow0 + (size_t)b * (E_EDGES * FIN);
            for (int p = j; p < 39; p += 4) {
                unsigned pv = 0;
                if (rvalid) { float2 f = *(const float2*)(xr + 2 * p); pv = packbf2(f.x, f.y); }
                *(unsigned*)(As + rr * SA_E + 2 * p) = pv;
            }
        }
        __syncthreads();

        f32x4 acc[4][4];
        zero_acc<4>(acc);
        run_layer<4>(As, SA_E, wpack + WOFF_E0, 5, w * 4, m15, q, lane, acc);   // K=160
        epi_to_H<4>(Hs, acc, eb0, w, m15, q);
        __syncthreads();

        zero_acc<4>(acc);
        run_layer<4>(Hs, SH, wpack + WOFF_E1, 8, w * 4, m15, q, lane, acc);     // K=256
        __syncthreads();
        epi_to_H<4>(Hs, acc, eb1, w, m15, q);
        __syncthreads();

        zero_acc<4>(acc);
        run_layer<4>(Hs, SH, wpack + WOFF_E2, 8, w * 4, m15, q, lane, acc);     // K=256

        // --- in-register segment reduce + atomic flush ---
        int ns = nseg;
        for (int s = 0; s < ns; ++s) {
            int lo = starts[s], hi = starts[s + 1];
            float sm[4];
#pragma unroll
            for (int nf = 0; nf < 4; ++nf) {
                float t = 0.f;
#pragma unroll
                for (int mf = 0; mf < 4; ++mf)
#pragma unroll
                    for (int r4 = 0; r4 < 4; ++r4) {
                        int row = mf * 16 + q * 4 + r4;
                        t += (row >= lo && row < hi) ? acc[mf][nf][r4] : 0.f;
                    }
                t += __shfl_xor(t, 16, 64);
                t += __shfl_xor(t, 32, 64);
                sm[nf] = t;
            }
            float v = sm[0], bb = bnf[0];
            if (q == 1) { v = sm[1]; bb = bnf[1]; }
            else if (q == 2) { v = sm[2]; bb = bnf[2]; }
            else if (q == 3) { v = sm[3]; bb = bnf[3]; }
            int dc = dstl[lo];
            atomicAdd(&agg[((size_t)b * NC + dc) * 256 + w * 64 + lane],
                      v + bb * (float)(hi - lo));
        }
        __syncthreads();   // fences L2's Hs reads & L0's As reads before next b overwrites
    }
}

// ---------------- node MLP (32-row tiles) ----------------
__global__ __launch_bounds__(256, 2) void node_mlp_kernel(
    const float* __restrict__ h3, const float* __restrict__ agg,
    const float* __restrict__ nb0, const float* __restrict__ nb1, const float* __restrict__ nb2,
    const unsigned short* __restrict__ wpack, float* __restrict__ out) {
    __shared__ __align__(16) unsigned short As[32 * SA_N];
    __shared__ __align__(16) unsigned short Hs[32 * SH];
    __shared__ int cl[32], vl[32];

    const int base = blockIdx.x * 32;
    const int tid = threadIdx.x, lane = tid & 63, w = tid >> 6;
    const int m15 = lane & 15, q = lane >> 4;

    if (tid < 32) {
        int jj = base + tid;
        vl[tid] = (jj < NROWS_NODE);
        cl[tid] = vl[tid] ? (jj % NC) : 0;
    }
    __syncthreads();

    for (int i = tid; i < 32 * 352; i += 256) {
        int r = i / 352, k = i - r * 352;
        float v = 0.f;
        if (vl[r]) {
            int jj = base + r;
            if (k < 78) v = h3[cl[r] * FIN + k];
            else if (k < 334) v = agg[(size_t)jj * 256 + (k - 78)];
        }
        As[r * SA_N + k] = f2bf(v);
    }
    __syncthreads();

    f32x4 acc[2][4];
    zero_acc<2>(acc);
    run_layer<2>(As, SA_N, wpack + WOFF_N0, 11, w * 4, m15, q, lane, acc);   // K=352
    epi_to_H<2>(Hs, acc, nb0, w, m15, q);
    __syncthreads();

    zero_acc<2>(acc);
    run_layer<2>(Hs, SH, wpack + WOFF_N1, 8, w * 4, m15, q, lane, acc);
    __syncthreads();
    epi_to_H<2>(Hs, acc, nb1, w, m15, q);
    __syncthreads();

    zero_acc<2>(acc);
    run_layer<2>(Hs, SH, wpack + WOFF_N2, 8, w * 4, m15, q, lane, acc);

#pragma unroll
    for (int nf = 0; nf < 4; ++nf) {
        int col = w * 64 + nf * 16 + m15;
        float bv = nb2[col];
#pragma unroll
        for (int mf = 0; mf < 2; ++mf)
#pragma unroll
            for (int r4 = 0; r4 < 4; ++r4) {
                int row = mf * 16 + q * 4 + r4;
                int jj = base + row;
                if (jj < NROWS_NODE) out[(size_t)jj * 256 + col] = acc[mf][nf][r4] + bv;
            }
    }
}

// ---------------- residual MLP (32-row tiles) ----------------
__global__ __launch_bounds__(256, 2) void res_mlp_kernel(
    const float* __restrict__ la, const float* __restrict__ rb0, const float* __restrict__ rb1,
    const float* __restrict__ rb2, const float* __restrict__ rWs, const float* __restrict__ rbs,
    const unsigned short* __restrict__ wpack, float* __restrict__ out) {
    __shared__ __align__(16) unsigned short As[32 * SA_R];
    __shared__ __align__(16) unsigned short Hs[32 * SH];

    const int base = blockIdx.x * 32;
    const int tid = threadIdx.x, lane = tid & 63, w = tid >> 6;
    const int m15 = lane & 15, q = lane >> 4;

    for (int i = tid; i < 32 * SA_R; i += 256) {
        int r = i / SA_R, k = i - r * SA_R;
        int e = base + r;
        float v = (e < E_LAT && k < 2) ? la[e * 2 + k] : 0.f;
        As[i] = f2bf(v);
    }
    __syncthreads();

    f32x4 acc[2][4];
    zero_acc<2>(acc);
    run_layer<2>(As, SA_R, wpack + WOFF_R0, 1, w * 4, m15, q, lane, acc);   // K=32 (2 real)
    epi_to_H<2>(Hs, acc, rb0, w, m15, q);
    __syncthreads();

    zero_acc<2>(acc);
    run_layer<2>(Hs, SH, wpack + WOFF_R1, 8, w * 4, m15, q, lane, acc);
    __syncthreads();
    epi_to_H<2>(Hs, acc, rb1, w, m15, q);
    __syncthreads();

    zero_acc<2>(acc);
    run_layer<2>(Hs, SH, wpack + WOFF_R2, 8, w * 4, m15, q, lane, acc);

#pragma unroll
    for (int nf = 0; nf < 4; ++nf) {
        int col = w * 64 + nf * 16 + m15;
        float bv = rb2[col] + rbs[col];
        float ws0 = rWs[col], ws1 = rWs[256 + col];
#pragma unroll
        for (int mf = 0; mf < 2; ++mf)
#pragma unroll
            for (int r4 = 0; r4 < 4; ++r4) {
                int row = mf * 16 + q * 4 + r4;
                int e = base + row;
                if (e < E_LAT) {
                    float v = acc[mf][nf][r4] + bv + la[e * 2] * ws0 + la[e * 2 + 1] * ws1;
                    out[(size_t)e * 256 + col] = v;
                }
            }
    }
}

__global__ void idx_copy_kernel(const int* __restrict__ lei, float* __restrict__ out) {
    int i = blockIdx.x * 256 + threadIdx.x;
    if (i < OUT_IDX_N) out[i] = (float)lei[i];
}

// ---------------- launch ----------------
extern "C" void kernel_launch(void* const* d_in, const int* in_sizes, int n_in,
                              void* d_out, int out_size, void* d_ws, size_t ws_size,
                              hipStream_t stream) {
    const float* x      = (const float*)d_in[0];
    const int*   eidx   = (const int*)d_in[1];
    const float* eattr  = (const float*)d_in[2];
    const int*   lei    = (const int*)d_in[3];
    const float* la     = (const float*)d_in[4];
    const float* h3     = (const float*)d_in[5];
    const float* eW0 = (const float*)d_in[6],  *eb0 = (const float*)d_in[7];
    const float* eW1 = (const float*)d_in[8],  *eb1 = (const float*)d_in[9];
    const float* eW2 = (const float*)d_in[10], *eb2 = (const float*)d_in[11];
    const float* nW0 = (const float*)d_in[12], *nb0 = (const float*)d_in[13];
    const float* nW1 = (const float*)d_in[14], *nb1 = (const float*)d_in[15];
    const float* nW2 = (const float*)d_in[16], *nb2 = (const float*)d_in[17];
    const float* rW0 = (const float*)d_in[18], *rb0 = (const float*)d_in[19];
    const float* rW1 = (const float*)d_in[20], *rb1 = (const float*)d_in[21];
    const float* rW2 = (const float*)d_in[22], *rb2 = (const float*)d_in[23];
    const float* rWs = (const float*)d_in[24], *rbs = (const float*)d_in[25];

    char* ws = (char*)d_ws;
    float* agg  = (float*)(ws + AGG_OFF);
    int* cnt    = (int*)(ws + CNT_OFF);
    int* cur    = (int*)(ws + CUR_OFF);
    int* perm   = (int*)(ws + PERM_OFF);
    unsigned short* wpack = (unsigned short*)(ws + WPACK_OFF);

    float* out = (float*)d_out;

    hipMemsetAsync(d_ws, 0, CUR_OFF, stream);   // agg + histogram counters

    pack_weights<<<1040, 512, 0, stream>>>(eW0, eW1, eW2, nW0, nW1, nW2, rW0, rW1, rW2, wpack);
    hist_kernel<<<254, 256, 0, stream>>>(eidx + E_EDGES, cnt);
    scan_kernel<<<1, 1024, 0, stream>>>(cnt, cur);
    scatter_kernel<<<254, 256, 0, stream>>>(eidx + E_EDGES, cur, perm);

    edge_mlp_kernel<<<NTILES_E, 256, 0, stream>>>(x, eidx, eattr, h3,
                                                  eb0, eb1, eb2, wpack, perm, agg);
    node_mlp_kernel<<<211, 256, 0, stream>>>(h3, agg, nb0, nb1, nb2, wpack, out);
    res_mlp_kernel<<<185, 256, 0, stream>>>(la, rb0, rb1, rb2, rWs, rbs, wpack,
                                            out + OUT_ATTR_OFF);
    idx_copy_kernel<<<47, 256, 0, stream>>>(lei, out + OUT_IDX_OFF);
}